// Round 5
// baseline (345.347 us; speedup 1.0000x reference)
//
#include <hip/hip_runtime.h>
#include <hip/hip_bf16.h>
#include <hip/hip_fp8.h>

#define N_ROWS 4096
#define IN_DIM 768
#define OUT_DIM 512

// All GEMM operands fragment-major, all K-loops barrier-free (no LDS staging).
// bf16 fragment-major (16x16 MFMA): unit = gt*(K/32)+kf, byte = (unit*64+lane)*16;
// lane elems: row = gt*16+(lane&15), k = kf*32+(lane>>4)*8+j.
// R18: gram moves to MX-scaled fp8 32x32x64 (mfma_scale_f32_32x32x64_f8f6f4,
//   unit scales 0x7F = 2^0 -> exact fp8 GEMM at 2.1x the 16x16 fp8 rate).
//   Rationale: MfmaUtil pinned ~37% across 5 schedules (R13-R17) -> per-wave
//   structural limit; only rate helps. MFMA floor 52->23us, same bytes/K-step.
//   Abuf re-laid out for 32x32 fragments: unit=(ks*256+g), g=row>>5 pair-local,
//   byte = unit*2048 + lane*32; lane holds row g*32+(lane&31),
//   k = ks*64+(lane>>5)*32+j. gemm2 readback writes this layout; gram epilogue
//   remapped to 32x32 C/D (col=lane&31, row=(reg&3)+8*(reg>>2)+4*(lane>>5)).
//   Rest = R17/R14 config (gemm1 dbuf 768x256, gemm2 dbuf 512thr).

using bf16x8 = __attribute__((ext_vector_type(8))) short;
using f32x4  = __attribute__((ext_vector_type(4))) float;
using f32x16 = __attribute__((ext_vector_type(16))) float;
using i32x8  = __attribute__((ext_vector_type(8))) int;
using i64    = long;
using i64x2  = __attribute__((ext_vector_type(2))) long;

__device__ __constant__ int c_docmap[6] = {0, 1, 0, 2, 1, 2};

__device__ inline unsigned short f2bf(float f) {
    __hip_bfloat16 h = __float2bfloat16(f);
    return reinterpret_cast<unsigned short&>(h);
}
__device__ inline float bf2f(unsigned short u) {
    return __uint_as_float((unsigned int)u << 16);
}
__device__ inline unsigned char f2fp8(float f) {
    __hip_fp8_e4m3 t(f);           // OCP e4m3fn, RNE+sat
    return t.__x;
}
__device__ inline uint4 pack8bf(const float* v) {
    uint4 o;
    unsigned short* p = (unsigned short*)&o;
#pragma unroll
    for (int j = 0; j < 8; ++j) p[j] = f2bf(v[j]);
    return o;
}

// ---------------- prep: conversions to fragment-major + zero-init ----------------
__global__ __launch_bounds__(256) void prep(
    const float* __restrict__ d0, const float* __restrict__ d1,
    const float* __restrict__ d2, const float* __restrict__ W1s,
    const float* __restrict__ W2s, unsigned short* __restrict__ Xb,
    unsigned short* __restrict__ W1t, unsigned short* __restrict__ W2t,
    char* __restrict__ zbase) {
    int wunit = blockIdx.x * 4 + (threadIdx.x >> 6);
    int lane = threadIdx.x & 63;
    int lane15 = lane & 15, quad = lane >> 4;
    if (wunit < 18432) {
        int d = wunit / 6144, u = wunit % 6144;       // 256 gt x 24 kf
        int gt = u / 24, kf = u % 24;
        const float* src = (d == 0) ? d0 : ((d == 1) ? d1 : d2);
        const float* s = src + (size_t)(gt * 16 + lane15) * IN_DIM + kf * 32 + quad * 8;
        float4 a = *(const float4*)s, b = *(const float4*)(s + 4);
        float v[8] = {a.x, a.y, a.z, a.w, b.x, b.y, b.z, b.w};
        *(uint4*)(Xb + (size_t)d * N_ROWS * IN_DIM + (size_t)u * 512 + lane * 8) = pack8bf(v);
    } else if (wunit < 23040) {
        int v0 = wunit - 18432;
        int z = v0 / 768, u = v0 % 768;               // 32 gt x 24 kf
        int gt = u / 24, kf = u % 24;
        int n = gt * 16 + lane15;
        int k0 = kf * 32 + quad * 8;
        const float* W = W1s + (size_t)z * IN_DIM * OUT_DIM;
        float v[8];
#pragma unroll
        for (int j = 0; j < 8; ++j) v[j] = W[(size_t)(k0 + j) * OUT_DIM + n];
        *(uint4*)(W1t + (size_t)z * OUT_DIM * IN_DIM + (size_t)u * 512 + lane * 8) = pack8bf(v);
    } else if (wunit < 26112) {
        int v0 = wunit - 23040;
        int z = v0 / 512, u = v0 % 512;               // 32 gt x 16 kf
        int gt = u / 16, kf = u % 16;
        int n = gt * 16 + lane15;
        int k0 = kf * 32 + quad * 8;
        const float* W = W2s + (size_t)z * OUT_DIM * OUT_DIM;
        float v[8];
#pragma unroll
        for (int j = 0; j < 8; ++j) v[j] = W[(size_t)(k0 + j) * OUT_DIM + n];
        *(uint4*)(W2t + (size_t)z * OUT_DIM * OUT_DIM + (size_t)u * 512 + lane * 8) = pack8bf(v);
    } else {
        size_t b = (size_t)(wunit - 26112) * 1024 + (size_t)lane * 16;
        if (b < (size_t)(24576 + 98304))
            *(float4*)(zbase + b) = (float4){0.f, 0.f, 0.f, 0.f};
    }
}

// ---------------- GEMM1: 256x128 supertile, barrier-free, BF16 out + BN-stats ----------------
// 4-wave blocks, grid 768 (= 8 * 96), XCD-contiguous, double-buffered (R14).
__global__ __launch_bounds__(256) void gemm1_bn(
    const unsigned short* __restrict__ Xb, const unsigned short* __restrict__ W1t,
    const float* __restrict__ biasAll, unsigned short* __restrict__ H,
    float* __restrict__ stats) {
    const int NKF = IN_DIM / 32;   // 24
    int px = blockIdx.x;
    int logical = (px & 7) * 96 + (px >> 3);      // 768 = 8 * 96
    int T = logical >> 1, sub = logical & 1;
    int z = T >> 6, rem = T & 63;
    int m0 = (rem >> 2) * 256, n0 = (rem & 3) * 128;
    const unsigned short* A = Xb + (size_t)c_docmap[z] * N_ROWS * IN_DIM;
    const unsigned short* B = W1t + (size_t)z * OUT_DIM * IN_DIM;
    const float* bz = biasAll + (size_t)z * OUT_DIM;
    unsigned short* C = H + (size_t)z * N_ROWS * OUT_DIM;

    int tid = threadIdx.x;
    int wave = (tid >> 6) + sub * 4, lane = tid & 63;
    int lane15 = lane & 15, quad = lane >> 4;
    int wrow = (wave >> 1) * 64, wcol = (wave & 1) * 64;

    const unsigned short* Ca = A + (size_t)((m0 + wrow) >> 4) * NKF * 512 + (size_t)lane * 8;
    const unsigned short* Cb = B + (size_t)((n0 + wcol) >> 4) * NKF * 512 + (size_t)lane * 8;

    f32x4 acc[4][4];
#pragma unroll
    for (int mt = 0; mt < 4; ++mt)
#pragma unroll
        for (int nt = 0; nt < 4; ++nt)
            acc[mt][nt] = (f32x4){0.f, 0.f, 0.f, 0.f};

    bf16x8 aC[4], bC[4], aN[4], bN[4];
#pragma unroll
    for (int t = 0; t < 4; ++t) {
        aC[t] = *(const bf16x8*)(Ca + (size_t)t * NKF * 512);
        bC[t] = *(const bf16x8*)(Cb + (size_t)t * NKF * 512);
    }
#pragma unroll
    for (int kf = 0; kf < NKF; ++kf) {
        if (kf < NKF - 1) {
#pragma unroll
            for (int t = 0; t < 4; ++t) {
                aN[t] = *(const bf16x8*)(Ca + (size_t)t * NKF * 512 + (kf + 1) * 512);
                bN[t] = *(const bf16x8*)(Cb + (size_t)t * NKF * 512 + (kf + 1) * 512);
            }
        }
        __builtin_amdgcn_s_setprio(1);
#pragma unroll
        for (int mt = 0; mt < 4; ++mt)
#pragma unroll
            for (int nt = 0; nt < 4; ++nt)
                acc[mt][nt] = __builtin_amdgcn_mfma_f32_16x16x32_bf16(aC[mt], bC[nt], acc[mt][nt], 0, 0, 0);
        __builtin_amdgcn_s_setprio(0);
#pragma unroll
        for (int t = 0; t < 4; ++t) { aC[t] = aN[t]; bC[t] = bN[t]; }
    }

    float s1[4] = {0.f, 0.f, 0.f, 0.f}, s2[4] = {0.f, 0.f, 0.f, 0.f};
#pragma unroll
    for (int nt = 0; nt < 4; ++nt) {
        int col = n0 + wcol + nt * 16 + lane15;
        float bv = bz[col];
#pragma unroll
        for (int mt = 0; mt < 4; ++mt)
#pragma unroll
            for (int r = 0; r < 4; ++r) {
                int row = m0 + wrow + mt * 16 + quad * 4 + r;
                float v = acc[mt][nt][r] + bv;
                C[(size_t)row * OUT_DIM + col] = f2bf(v);
                s1[nt] += v; s2[nt] += v * v;       // stats from fp32 (exact)
            }
    }
#pragma unroll
    for (int nt = 0; nt < 4; ++nt) {
        float a = s1[nt], b = s2[nt];
        a += __shfl_xor(a, 16); a += __shfl_xor(a, 32);
        b += __shfl_xor(b, 16); b += __shfl_xor(b, 32);
        if (quad == 0) {
            int col = n0 + wcol + nt * 16 + lane15;
            atomicAdd(&stats[((size_t)z * OUT_DIM + col) * 2 + 0], a);
            atomicAdd(&stats[((size_t)z * OUT_DIM + col) * 2 + 1], b);
        }
    }
}

// ---------------- BN apply + ReLU: bf16 H row-major -> bf16 Hb FRAG-MAJOR ----------------
__global__ __launch_bounds__(256) void bn_apply(
    const unsigned short* __restrict__ H, unsigned short* __restrict__ Hb,
    const float* __restrict__ stats, const float* __restrict__ gammas,
    const float* __restrict__ betas) {
    int wunit = blockIdx.x * 4 + (threadIdx.x >> 6);
    if (wunit >= 24576) return;
    int lane = threadIdx.x & 63;
    int lane15 = lane & 15, quad = lane >> 4;
    int z = wunit / 4096, u = wunit % 4096;       // 256 gt x 16 kf
    int gt = u / 16, kf = u % 16;
    int row = gt * 16 + lane15;
    int k = kf * 32 + quad * 8;
    uint4 hu = *(const uint4*)(H + ((size_t)z * N_ROWS + row) * OUT_DIM + k);
    unsigned int w[4] = {hu.x, hu.y, hu.z, hu.w};
    float v[8];
#pragma unroll
    for (int j = 0; j < 8; ++j) {
        unsigned short us = (j & 1) ? (unsigned short)(w[j >> 1] >> 16)
                                    : (unsigned short)(w[j >> 1] & 0xffff);
        size_t sc = (size_t)z * OUT_DIM + k + j;
        float mu = stats[sc * 2 + 0] * (1.f / N_ROWS);
        float var = stats[sc * 2 + 1] * (1.f / N_ROWS) - mu * mu;
        float s = gammas[sc] * rsqrtf(var + 1e-5f);
        v[j] = fmaxf(fmaf(bf2f(us), s, betas[sc] - mu * s), 0.f);
    }
    *(uint4*)(Hb + (size_t)z * N_ROWS * OUT_DIM + (size_t)u * 512 + lane * 8) = pack8bf(v);
}

// ---------------- GEMM2 fused: barrier-free K-loop + l2norm/fp8/transpose epilogue ----------------
// 64 rows x 512 cols per block. 1D grid 384, XCD-contiguous (z-major).
// Double-buffered; 512 thr (cross-wave LDS epilogue). Readback now emits the
// 32x32-fragment MX layout: pair slab (z>>1), unit = ks*256 + g (g = pair-local
// row>>5), byte = unit*2048 + lane*32; lane holds row g*32+(lane&31),
// k-bytes ks*64 + (lane>>5)*32 + 0..31. wave = ks.
__global__ __launch_bounds__(512) void gemm2_fused(
    const unsigned short* __restrict__ Hb, const unsigned short* __restrict__ W2t,
    const float* __restrict__ biasAll, unsigned char* __restrict__ Abuf) {
    const int NKF = OUT_DIM / 32;  // 16
    int px = blockIdx.x;
    int L = (px & 7) * 48 + (px >> 3);            // 384 = 8 * 48
    int z = L >> 6;
    int m0 = (L & 63) * 64;
    const unsigned short* A = Hb + (size_t)z * N_ROWS * OUT_DIM;
    const unsigned short* B = W2t + (size_t)z * OUT_DIM * OUT_DIM;
    const float* bz = biasAll + (size_t)z * OUT_DIM;

    int tid = threadIdx.x;
    int wave = tid >> 6, lane = tid & 63;
    int lane15 = lane & 15, quad = lane >> 4;
    int wcol = wave * 64;

    const unsigned short* Ca = A + (size_t)(m0 >> 4) * NKF * 512 + (size_t)lane * 8;
    const unsigned short* Cb = B + (size_t)(wave * 4) * NKF * 512 + (size_t)lane * 8;

    f32x4 acc[4][4];
#pragma unroll
    for (int mt = 0; mt < 4; ++mt)
#pragma unroll
        for (int nt = 0; nt < 4; ++nt)
            acc[mt][nt] = (f32x4){0.f, 0.f, 0.f, 0.f};

    bf16x8 aC[4], bC[4], aN[4], bN[4];
#pragma unroll
    for (int t = 0; t < 4; ++t) {
        aC[t] = *(const bf16x8*)(Ca + (size_t)t * NKF * 512);
        bC[t] = *(const bf16x8*)(Cb + (size_t)t * NKF * 512);
    }
#pragma unroll
    for (int kf = 0; kf < NKF; ++kf) {
        if (kf < NKF - 1) {
#pragma unroll
            for (int t = 0; t < 4; ++t) {
                aN[t] = *(const bf16x8*)(Ca + (size_t)t * NKF * 512 + (kf + 1) * 512);
                bN[t] = *(const bf16x8*)(Cb + (size_t)t * NKF * 512 + (kf + 1) * 512);
            }
        }
#pragma unroll
        for (int mt = 0; mt < 4; ++mt)
#pragma unroll
            for (int nt = 0; nt < 4; ++nt)
                acc[mt][nt] = __builtin_amdgcn_mfma_f32_16x16x32_bf16(aC[mt], bC[nt], acc[mt][nt], 0, 0, 0);
#pragma unroll
        for (int t = 0; t < 4; ++t) { aC[t] = aN[t]; bC[t] = bN[t]; }
    }

    // ---- epilogue: bias, row sumsq, normalize, fp8, transpose (validated R11/R12) ----
    __shared__ float part[8][64];
    __shared__ float scf[64];
    __shared__ __attribute__((aligned(16))) unsigned char T[64 * 520];

    float rs[16];
#pragma unroll
    for (int j = 0; j < 16; ++j) rs[j] = 0.f;
#pragma unroll
    for (int nt = 0; nt < 4; ++nt) {
        float bv = bz[wcol + nt * 16 + lane15];
#pragma unroll
        for (int mt = 0; mt < 4; ++mt)
#pragma unroll
            for (int r = 0; r < 4; ++r) {
                float v = acc[mt][nt][r] + bv;
                acc[mt][nt][r] = v;
                rs[mt * 4 + r] += v * v;
            }
    }
#pragma unroll
    for (int j = 0; j < 16; ++j) {
        float v = rs[j];
        v += __shfl_xor(v, 1); v += __shfl_xor(v, 2);
        v += __shfl_xor(v, 4); v += __shfl_xor(v, 8);
        rs[j] = v;
    }
    if (lane15 == 0) {
#pragma unroll
        for (int j = 0; j < 16; ++j)
            part[wave][(j >> 2) * 16 + quad * 4 + (j & 3)] = rs[j];
    }
    __syncthreads();
    if (tid < 64) {
        float ss = 0.f;
#pragma unroll
        for (int w = 0; w < 8; ++w) ss += part[w][tid];
        scf[tid] = 1.f / fmaxf(sqrtf(ss), 1e-12f);
    }
    __syncthreads();
#pragma unroll
    for (int mt = 0; mt < 4; ++mt)
#pragma unroll
        for (int r = 0; r < 4; ++r) {
            int row = mt * 16 + quad * 4 + r;
            float s = scf[row];
#pragma unroll
            for (int nt = 0; nt < 4; ++nt)
                T[row * 520 + wcol + nt * 16 + lane15] = f2fp8(acc[mt][nt][r] * s);
        }
    __syncthreads();
    // readback into MX 32x32-fragment layout. wave = ks (8 k-steps of 64).
    {
        int l31 = lane & 31, lh = lane >> 5;
        unsigned char* Ap = Abuf + (size_t)(z >> 1) * ((size_t)2 * N_ROWS * OUT_DIM);
        int baseg = (z & 1) * 128 + (m0 >> 5);
#pragma unroll
        for (int g = 0; g < 2; ++g) {
            const unsigned char* src = T + (g * 32 + l31) * 520 + wave * 64 + lh * 32;
            i64 w0 = *(const i64*)(src);
            i64 w1 = *(const i64*)(src + 8);
            i64 w2 = *(const i64*)(src + 16);
            i64 w3 = *(const i64*)(src + 24);
            unsigned char* dst = Ap + ((size_t)(wave * 256 + baseg + g) * 64 + lane) * 32;
            i64x2 s0; s0[0] = w0; s0[1] = w1;
            i64x2 s1; s1[0] = w2; s1[1] = w3;
            *(i64x2*)dst = s0;
            *(i64x2*)(dst + 16) = s1;
        }
    }
}

// ---------------- barrier-free MX-fp8 Gram: 256x128 supertile, J>=2I masked ----------------
// R18: mfma_scale_f32_32x32x64_f8f6f4 with unit scales (0x7F7F7F7F = 2^0) ->
// exact fp8 GEMM at 2.1x rate. Per logical wave: 64x64 tile = 2x2 of 32x32,
// acc[2][2] f32x16 (64 AGPRs, same as before). 8 k-steps of 64; per step
// 4 x i32x8 operand loads (128 B/lane, same bytes as R17). C/D map:
// col = lane&31, row = (reg&3)+8*(reg>>2)+4*(lane>>5)  [HW-verified m74/m101].
__global__ __launch_bounds__(256, 3) void gram_kernel(const unsigned char* __restrict__ Abase,
                                                      float* __restrict__ rowsum,
                                                      float* __restrict__ crossdot) {
    int px = blockIdx.x;
    int logical = (px & 7) * 792 + (px >> 3);     // 6336 = 8 * 792
    int tile = logical >> 1, sub = logical & 1;
    int p = tile / 1056;
    int t0 = tile - p * 1056;
    const unsigned char* Cm = Abase + (size_t)p * 2 * N_ROWS * OUT_DIM;

    int I = 0;
    while (t0 >= 64 - 2 * I) { t0 -= 64 - 2 * I; ++I; }
    int J = 2 * I + t0;
    int m0 = I * 256, n0 = J * 128;

    int tid = threadIdx.x;
    int wave = (tid >> 6) + sub * 4, lane = tid & 63;
    int l31 = lane & 31, lh = lane >> 5;
    int R0 = m0 + (wave >> 1) * 64;               // 64 rows per logical wave
    int C0 = n0 + (wave & 1) * 64;                // 64 cols per logical wave

    const unsigned char* Ca = Cm + (size_t)(R0 >> 5) * 2048 + (size_t)lane * 32;
    const unsigned char* Cb = Cm + (size_t)(C0 >> 5) * 2048 + (size_t)lane * 32;

    f32x16 acc[2][2];
#pragma unroll
    for (int mt = 0; mt < 2; ++mt)
#pragma unroll
        for (int nt = 0; nt < 2; ++nt)
#pragma unroll
            for (int r = 0; r < 16; ++r) acc[mt][nt][r] = 0.f;

#pragma unroll 1
    for (int ks = 0; ks < 8; ++ks) {
        size_t kb = (size_t)ks << 19;             // ks * 256 units * 2048 B
        i32x8 a0 = *(const i32x8*)(Ca + kb);
        i32x8 a1 = *(const i32x8*)(Ca + kb + 2048);
        i32x8 b0 = *(const i32x8*)(Cb + kb);
        i32x8 b1 = *(const i32x8*)(Cb + kb + 2048);
        acc[0][0] = __builtin_amdgcn_mfma_scale_f32_32x32x64_f8f6f4(
            a0, b0, acc[0][0], 0, 0, 0, 0x7F7F7F7F, 0, 0x7F7F7F7F);
        acc[0][1] = __builtin_amdgcn_mfma_scale_f32_32x32x64_f8f6f4(
            a0, b1, acc[0][1], 0, 0, 0, 0x7F7F7F7F, 0, 0x7F7F7F7F);
        acc[1][0] = __builtin_amdgcn_mfma_scale_f32_32x32x64_f8f6f4(
            a1, b0, acc[1][0], 0, 0, 0, 0x7F7F7F7F, 0, 0x7F7F7F7F);
        acc[1][1] = __builtin_amdgcn_mfma_scale_f32_32x32x64_f8f6f4(
            a1, b1, acc[1][1], 0, 0, 0, 0x7F7F7F7F, 0, 0x7F7F7F7F);
    }

    float* cdp = crossdot + (size_t)p * 2 * N_ROWS;
    float* rp  = rowsum  + (size_t)p * 2 * N_ROWS;

    float rs[2][16];
    float cs[2] = {0.f, 0.f};
#pragma unroll
    for (int mt = 0; mt < 2; ++mt)
#pragma unroll
        for (int r = 0; r < 16; ++r) rs[mt][r] = 0.f;

    if (J >= 2 * I + 2) {
#pragma unroll
        for (int mt = 0; mt < 2; ++mt)
#pragma unroll
            for (int nt = 0; nt < 2; ++nt)
#pragma unroll
                for (int r = 0; r < 16; ++r) {
                    float e = __expf(2.f * acc[mt][nt][r]);
                    rs[mt][r] += e;
                    cs[nt] += e;
                }
        if (J >= 32 && ((J - 32) >> 1) == I) {
#pragma unroll
            for (int mt = 0; mt < 2; ++mt)
#pragma unroll
                for (int nt = 0; nt < 2; ++nt) {
                    int gcol = C0 + nt * 32 + l31;
#pragma unroll
                    for (int r = 0; r < 16; ++r) {
                        int grow = R0 + mt * 32 + (r & 3) + 8 * (r >> 2) + 4 * lh;
                        if (gcol == grow + N_ROWS) {
                            float s = acc[mt][nt][r];
                            cdp[grow] = s;
                            cdp[gcol] = s;
                        }
                    }
                }
        }
    } else {
#pragma unroll
        for (int mt = 0; mt < 2; ++mt)
#pragma unroll
            for (int nt = 0; nt < 2; ++nt) {
                int gcol = C0 + nt * 32 + l31;
#pragma unroll
                for (int r = 0; r < 16; ++r) {
                    int grow = R0 + mt * 32 + (r & 3) + 8 * (r >> 2) + 4 * lh;
                    if (grow < gcol) {
                        float e = __expf(2.f * acc[mt][nt][r]);
                        rs[mt][r] += e;
                        cs[nt] += e;
                    }
                }
            }
    }

    // row-sums: reduce across the 32 lanes of each half (rows differ by half)
#pragma unroll
    for (int mt = 0; mt < 2; ++mt)
#pragma unroll
        for (int r = 0; r < 16; ++r) {
            float v = rs[mt][r];
            v += __shfl_xor(v, 1); v += __shfl_xor(v, 2);
            v += __shfl_xor(v, 4); v += __shfl_xor(v, 8);
            v += __shfl_xor(v, 16);
            rs[mt][r] = v;
        }
    if (l31 == 0) {
#pragma unroll
        for (int mt = 0; mt < 2; ++mt)
#pragma unroll
            for (int r = 0; r < 16; ++r) {
                int grow = R0 + mt * 32 + (r & 3) + 8 * (r >> 2) + 4 * lh;
                atomicAdd(&rp[grow], rs[mt][r]);
            }
    }
    // col-sums: combine the two halves (same col, disjoint rows)
#pragma unroll
    for (int nt = 0; nt < 2; ++nt) cs[nt] += __shfl_xor(cs[nt], 32);
    if (lane < 32) {
#pragma unroll
        for (int nt = 0; nt < 2; ++nt)
            atomicAdd(&rp[C0 + nt * 32 + lane], cs[nt]);
    }
}

// ---------------- final loss reduction: 96 blocks + device atomic ----------------
__global__ void loss_kernel(const float* __restrict__ rowsum,
                            const float* __restrict__ crossdot, float* __restrict__ out) {
    int i = blockIdx.x * 256 + threadIdx.x;       // 96*256 = 24576 exactly
    float v = logf(rowsum[i]) - 2.f * crossdot[i];
#pragma unroll
    for (int m = 1; m < 64; m <<= 1) v += __shfl_xor(v, m);
    __shared__ float red[4];
    if ((threadIdx.x & 63) == 0) red[threadIdx.x >> 6] = v;
    __syncthreads();
    if (threadIdx.x == 0)
        atomicAdd(out, (red[0] + red[1] + red[2] + red[3]) * (1.f / 24576.f));
}

// ---------------- launch ----------------
extern "C" void kernel_launch(void* const* d_in, const int* in_sizes, int n_in,
                              void* d_out, int out_size, void* d_ws, size_t ws_size,
                              hipStream_t stream) {
    const float* doc0   = (const float*)d_in[0];
    const float* doc1   = (const float*)d_in[1];
    const float* doc2   = (const float*)d_in[2];
    const float* W1s    = (const float*)d_in[3];
    const float* b1s    = (const float*)d_in[4];
    const float* gammas = (const float*)d_in[5];
    const float* betas  = (const float*)d_in[6];
    const float* W2s    = (const float*)d_in[7];
    const float* b2s    = (const float*)d_in[8];
    float* out = (float*)d_out;

    char* base = (char*)d_ws;
    size_t off = 0;
    auto alloc = [&](size_t bytes) -> char* {
        char* r = base + off;
        off += (bytes + 255) & ~(size_t)255;
        return r;
    };

    unsigned short* Xb   = (unsigned short*)alloc((size_t)3 * N_ROWS * IN_DIM * 2);
    unsigned short* W1t  = (unsigned short*)alloc((size_t)6 * OUT_DIM * IN_DIM * 2);
    unsigned short* W2t  = (unsigned short*)alloc((size_t)6 * OUT_DIM * OUT_DIM * 2);
    unsigned short* H    = (unsigned short*)alloc((size_t)6 * N_ROWS * OUT_DIM * 2);
    unsigned short* Hb   = (unsigned short*)alloc((size_t)6 * N_ROWS * OUT_DIM * 2);
    unsigned char*  Abuf = (unsigned char*)Xb;    // Xb dead after gemm1; 12 MB <= Xb
    char* zbase = alloc(24576 + 98304);
    float* stats  = (float*)zbase;
    float* rowsum = (float*)(zbase + 24576);
    float* cdot   = (float*)alloc((size_t)3 * 2 * N_ROWS * 4);

    if (ws_size < off) return;

    hipMemsetAsync(out, 0, sizeof(float), stream);   // loss accumulates atomically

    // 26112 conversion wave-units + 120 zero units = 26232 -> 6558 blocks
    prep<<<6558, 256, 0, stream>>>(doc0, doc1, doc2, W1s, W2s, Xb, W1t, W2t, zbase);

    gemm1_bn<<<768, 256, 0, stream>>>(Xb, W1t, b1s, H, stats);

    bn_apply<<<6144, 256, 0, stream>>>(H, Hb, stats, gammas, betas);

    gemm2_fused<<<384, 512, 0, stream>>>(Hb, W2t, b2s, Abuf);

    // supertile gram: 3 pairs x 1056 (J>=2I) tile-pairs, split into 4-wave blocks
    gram_kernel<<<6336, 256, 0, stream>>>(Abuf, rowsum, cdot);

    loss_kernel<<<96, 256, 0, stream>>>(rowsum, cdot, out);
}

// Round 6
// 283.809 us; speedup vs baseline: 1.2168x; 1.2168x over previous
//
#include <hip/hip_runtime.h>
#include <hip/hip_bf16.h>
#include <hip/hip_fp8.h>

#define N_ROWS 4096
#define IN_DIM 768
#define OUT_DIM 512

// All GEMM operands fragment-major, all K-loops barrier-free (no LDS staging).
// Fragment-major (R rows, K cols): unit = gt*(K/32)+kf (gt=row>>4, kf=k>>5),
// byte addr = (unit*64+lane)*16; lane elems: row = gt*16+(lane&15),
// k = kf*32+(lane>>4)*8+j. bf16: 8 elems/lane; fp8: 16 = 2 frags (lo=even kf).
// Abuf (fp8) is gt-major (R14 layout — kh-major cost ~20us in gemm2, 2 runs).
// R19: best-of-breed assembly after R15-R18 experiments:
//   - gram: 16x16 fp8 (MX 32x32x64 halved pipe time but doubled wall time —
//     4 MFMAs/step can't cover load latency; reverted). R15 micro-config:
//     4-wave blocks, single-buffered unroll-1 K-loop, launch_bounds(256,3)
//     (72 VGPR -> 3 blocks/CU), grid 6336, gt-major addressing.
//   - gemm1: R14 dbuf + setprio, 768x256, XCD-contiguous.
//   - gemm2: R14 exact (dbuf, gt-major Az readback).
//   MfmaUtil ~37% is this barrier-free structure's ceiling (matches m97
//   2-phase ceiling); breaking it needs the 8-phase LDS pipeline.

using bf16x8 = __attribute__((ext_vector_type(8))) short;
using f32x4  = __attribute__((ext_vector_type(4))) float;
using i64    = long;
using i64x2  = __attribute__((ext_vector_type(2))) long;

__device__ __constant__ int c_docmap[6] = {0, 1, 0, 2, 1, 2};

__device__ inline unsigned short f2bf(float f) {
    __hip_bfloat16 h = __float2bfloat16(f);
    return reinterpret_cast<unsigned short&>(h);
}
__device__ inline float bf2f(unsigned short u) {
    return __uint_as_float((unsigned int)u << 16);
}
__device__ inline unsigned char f2fp8(float f) {
    __hip_fp8_e4m3 t(f);           // OCP e4m3fn, RNE+sat
    return t.__x;
}
__device__ inline uint4 pack8bf(const float* v) {
    uint4 o;
    unsigned short* p = (unsigned short*)&o;
#pragma unroll
    for (int j = 0; j < 8; ++j) p[j] = f2bf(v[j]);
    return o;
}

// ---------------- prep: conversions to fragment-major + zero-init ----------------
__global__ __launch_bounds__(256) void prep(
    const float* __restrict__ d0, const float* __restrict__ d1,
    const float* __restrict__ d2, const float* __restrict__ W1s,
    const float* __restrict__ W2s, unsigned short* __restrict__ Xb,
    unsigned short* __restrict__ W1t, unsigned short* __restrict__ W2t,
    char* __restrict__ zbase) {
    int wunit = blockIdx.x * 4 + (threadIdx.x >> 6);
    int lane = threadIdx.x & 63;
    int lane15 = lane & 15, quad = lane >> 4;
    if (wunit < 18432) {
        int d = wunit / 6144, u = wunit % 6144;       // 256 gt x 24 kf
        int gt = u / 24, kf = u % 24;
        const float* src = (d == 0) ? d0 : ((d == 1) ? d1 : d2);
        const float* s = src + (size_t)(gt * 16 + lane15) * IN_DIM + kf * 32 + quad * 8;
        float4 a = *(const float4*)s, b = *(const float4*)(s + 4);
        float v[8] = {a.x, a.y, a.z, a.w, b.x, b.y, b.z, b.w};
        *(uint4*)(Xb + (size_t)d * N_ROWS * IN_DIM + (size_t)u * 512 + lane * 8) = pack8bf(v);
    } else if (wunit < 23040) {
        int v0 = wunit - 18432;
        int z = v0 / 768, u = v0 % 768;               // 32 gt x 24 kf
        int gt = u / 24, kf = u % 24;
        int n = gt * 16 + lane15;
        int k0 = kf * 32 + quad * 8;
        const float* W = W1s + (size_t)z * IN_DIM * OUT_DIM;
        float v[8];
#pragma unroll
        for (int j = 0; j < 8; ++j) v[j] = W[(size_t)(k0 + j) * OUT_DIM + n];
        *(uint4*)(W1t + (size_t)z * OUT_DIM * IN_DIM + (size_t)u * 512 + lane * 8) = pack8bf(v);
    } else if (wunit < 26112) {
        int v0 = wunit - 23040;
        int z = v0 / 512, u = v0 % 512;               // 32 gt x 16 kf
        int gt = u / 16, kf = u % 16;
        int n = gt * 16 + lane15;
        int k0 = kf * 32 + quad * 8;
        const float* W = W2s + (size_t)z * OUT_DIM * OUT_DIM;
        float v[8];
#pragma unroll
        for (int j = 0; j < 8; ++j) v[j] = W[(size_t)(k0 + j) * OUT_DIM + n];
        *(uint4*)(W2t + (size_t)z * OUT_DIM * OUT_DIM + (size_t)u * 512 + lane * 8) = pack8bf(v);
    } else {
        size_t b = (size_t)(wunit - 26112) * 1024 + (size_t)lane * 16;
        if (b < (size_t)(24576 + 98304))
            *(float4*)(zbase + b) = (float4){0.f, 0.f, 0.f, 0.f};
    }
}

// ---------------- GEMM1: 256x128 supertile, barrier-free, BF16 out + BN-stats ----------------
// 4-wave blocks, grid 768 (= 8 * 96), XCD-contiguous, double-buffered (R14).
__global__ __launch_bounds__(256) void gemm1_bn(
    const unsigned short* __restrict__ Xb, const unsigned short* __restrict__ W1t,
    const float* __restrict__ biasAll, unsigned short* __restrict__ H,
    float* __restrict__ stats) {
    const int NKF = IN_DIM / 32;   // 24
    int px = blockIdx.x;
    int logical = (px & 7) * 96 + (px >> 3);      // 768 = 8 * 96
    int T = logical >> 1, sub = logical & 1;
    int z = T >> 6, rem = T & 63;
    int m0 = (rem >> 2) * 256, n0 = (rem & 3) * 128;
    const unsigned short* A = Xb + (size_t)c_docmap[z] * N_ROWS * IN_DIM;
    const unsigned short* B = W1t + (size_t)z * OUT_DIM * IN_DIM;
    const float* bz = biasAll + (size_t)z * OUT_DIM;
    unsigned short* C = H + (size_t)z * N_ROWS * OUT_DIM;

    int tid = threadIdx.x;
    int wave = (tid >> 6) + sub * 4, lane = tid & 63;
    int lane15 = lane & 15, quad = lane >> 4;
    int wrow = (wave >> 1) * 64, wcol = (wave & 1) * 64;

    const unsigned short* Ca = A + (size_t)((m0 + wrow) >> 4) * NKF * 512 + (size_t)lane * 8;
    const unsigned short* Cb = B + (size_t)((n0 + wcol) >> 4) * NKF * 512 + (size_t)lane * 8;

    f32x4 acc[4][4];
#pragma unroll
    for (int mt = 0; mt < 4; ++mt)
#pragma unroll
        for (int nt = 0; nt < 4; ++nt)
            acc[mt][nt] = (f32x4){0.f, 0.f, 0.f, 0.f};

    bf16x8 aC[4], bC[4], aN[4], bN[4];
#pragma unroll
    for (int t = 0; t < 4; ++t) {
        aC[t] = *(const bf16x8*)(Ca + (size_t)t * NKF * 512);
        bC[t] = *(const bf16x8*)(Cb + (size_t)t * NKF * 512);
    }
#pragma unroll
    for (int kf = 0; kf < NKF; ++kf) {
        if (kf < NKF - 1) {
#pragma unroll
            for (int t = 0; t < 4; ++t) {
                aN[t] = *(const bf16x8*)(Ca + (size_t)t * NKF * 512 + (kf + 1) * 512);
                bN[t] = *(const bf16x8*)(Cb + (size_t)t * NKF * 512 + (kf + 1) * 512);
            }
        }
        __builtin_amdgcn_s_setprio(1);
#pragma unroll
        for (int mt = 0; mt < 4; ++mt)
#pragma unroll
            for (int nt = 0; nt < 4; ++nt)
                acc[mt][nt] = __builtin_amdgcn_mfma_f32_16x16x32_bf16(aC[mt], bC[nt], acc[mt][nt], 0, 0, 0);
        __builtin_amdgcn_s_setprio(0);
#pragma unroll
        for (int t = 0; t < 4; ++t) { aC[t] = aN[t]; bC[t] = bN[t]; }
    }

    float s1[4] = {0.f, 0.f, 0.f, 0.f}, s2[4] = {0.f, 0.f, 0.f, 0.f};
#pragma unroll
    for (int nt = 0; nt < 4; ++nt) {
        int col = n0 + wcol + nt * 16 + lane15;
        float bv = bz[col];
#pragma unroll
        for (int mt = 0; mt < 4; ++mt)
#pragma unroll
            for (int r = 0; r < 4; ++r) {
                int row = m0 + wrow + mt * 16 + quad * 4 + r;
                float v = acc[mt][nt][r] + bv;
                C[(size_t)row * OUT_DIM + col] = f2bf(v);
                s1[nt] += v; s2[nt] += v * v;       // stats from fp32 (exact)
            }
    }
#pragma unroll
    for (int nt = 0; nt < 4; ++nt) {
        float a = s1[nt], b = s2[nt];
        a += __shfl_xor(a, 16); a += __shfl_xor(a, 32);
        b += __shfl_xor(b, 16); b += __shfl_xor(b, 32);
        if (quad == 0) {
            int col = n0 + wcol + nt * 16 + lane15;
            atomicAdd(&stats[((size_t)z * OUT_DIM + col) * 2 + 0], a);
            atomicAdd(&stats[((size_t)z * OUT_DIM + col) * 2 + 1], b);
        }
    }
}

// ---------------- BN apply + ReLU: bf16 H row-major -> bf16 Hb FRAG-MAJOR ----------------
__global__ __launch_bounds__(256) void bn_apply(
    const unsigned short* __restrict__ H, unsigned short* __restrict__ Hb,
    const float* __restrict__ stats, const float* __restrict__ gammas,
    const float* __restrict__ betas) {
    int wunit = blockIdx.x * 4 + (threadIdx.x >> 6);
    if (wunit >= 24576) return;
    int lane = threadIdx.x & 63;
    int lane15 = lane & 15, quad = lane >> 4;
    int z = wunit / 4096, u = wunit % 4096;       // 256 gt x 16 kf
    int gt = u / 16, kf = u % 16;
    int row = gt * 16 + lane15;
    int k = kf * 32 + quad * 8;
    uint4 hu = *(const uint4*)(H + ((size_t)z * N_ROWS + row) * OUT_DIM + k);
    unsigned int w[4] = {hu.x, hu.y, hu.z, hu.w};
    float v[8];
#pragma unroll
    for (int j = 0; j < 8; ++j) {
        unsigned short us = (j & 1) ? (unsigned short)(w[j >> 1] >> 16)
                                    : (unsigned short)(w[j >> 1] & 0xffff);
        size_t sc = (size_t)z * OUT_DIM + k + j;
        float mu = stats[sc * 2 + 0] * (1.f / N_ROWS);
        float var = stats[sc * 2 + 1] * (1.f / N_ROWS) - mu * mu;
        float s = gammas[sc] * rsqrtf(var + 1e-5f);
        v[j] = fmaxf(fmaf(bf2f(us), s, betas[sc] - mu * s), 0.f);
    }
    *(uint4*)(Hb + (size_t)z * N_ROWS * OUT_DIM + (size_t)u * 512 + lane * 8) = pack8bf(v);
}

// ---------------- GEMM2 fused: barrier-free K-loop + l2norm/fp8/transpose epilogue ----------------
// 64 rows x 512 cols per block. 1D grid 384, XCD-contiguous (z-major).
// Double-buffered (R14); 512 thr (cross-wave LDS epilogue). gt-major Az write.
__global__ __launch_bounds__(512) void gemm2_fused(
    const unsigned short* __restrict__ Hb, const unsigned short* __restrict__ W2t,
    const float* __restrict__ biasAll, unsigned char* __restrict__ Abuf) {
    const int NKF = OUT_DIM / 32;  // 16
    int px = blockIdx.x;
    int L = (px & 7) * 48 + (px >> 3);            // 384 = 8 * 48
    int z = L >> 6;
    int m0 = (L & 63) * 64;
    const unsigned short* A = Hb + (size_t)z * N_ROWS * OUT_DIM;
    const unsigned short* B = W2t + (size_t)z * OUT_DIM * OUT_DIM;
    const float* bz = biasAll + (size_t)z * OUT_DIM;
    unsigned char* Az = Abuf + (size_t)z * N_ROWS * OUT_DIM;

    int tid = threadIdx.x;
    int wave = tid >> 6, lane = tid & 63;
    int lane15 = lane & 15, quad = lane >> 4;
    int wcol = wave * 64;

    const unsigned short* Ca = A + (size_t)(m0 >> 4) * NKF * 512 + (size_t)lane * 8;
    const unsigned short* Cb = B + (size_t)(wave * 4) * NKF * 512 + (size_t)lane * 8;

    f32x4 acc[4][4];
#pragma unroll
    for (int mt = 0; mt < 4; ++mt)
#pragma unroll
        for (int nt = 0; nt < 4; ++nt)
            acc[mt][nt] = (f32x4){0.f, 0.f, 0.f, 0.f};

    bf16x8 aC[4], bC[4], aN[4], bN[4];
#pragma unroll
    for (int t = 0; t < 4; ++t) {
        aC[t] = *(const bf16x8*)(Ca + (size_t)t * NKF * 512);
        bC[t] = *(const bf16x8*)(Cb + (size_t)t * NKF * 512);
    }
#pragma unroll
    for (int kf = 0; kf < NKF; ++kf) {
        if (kf < NKF - 1) {
#pragma unroll
            for (int t = 0; t < 4; ++t) {
                aN[t] = *(const bf16x8*)(Ca + (size_t)t * NKF * 512 + (kf + 1) * 512);
                bN[t] = *(const bf16x8*)(Cb + (size_t)t * NKF * 512 + (kf + 1) * 512);
            }
        }
#pragma unroll
        for (int mt = 0; mt < 4; ++mt)
#pragma unroll
            for (int nt = 0; nt < 4; ++nt)
                acc[mt][nt] = __builtin_amdgcn_mfma_f32_16x16x32_bf16(aC[mt], bC[nt], acc[mt][nt], 0, 0, 0);
#pragma unroll
        for (int t = 0; t < 4; ++t) { aC[t] = aN[t]; bC[t] = bN[t]; }
    }

    // ---- epilogue (validated R11/R12): bias, row sumsq, normalize, fp8, transpose ----
    __shared__ float part[8][64];
    __shared__ float scf[64];
    __shared__ __attribute__((aligned(16))) unsigned char T[64 * 520];

    float rs[16];
#pragma unroll
    for (int j = 0; j < 16; ++j) rs[j] = 0.f;
#pragma unroll
    for (int nt = 0; nt < 4; ++nt) {
        float bv = bz[wcol + nt * 16 + lane15];
#pragma unroll
        for (int mt = 0; mt < 4; ++mt)
#pragma unroll
            for (int r = 0; r < 4; ++r) {
                float v = acc[mt][nt][r] + bv;
                acc[mt][nt][r] = v;
                rs[mt * 4 + r] += v * v;
            }
    }
#pragma unroll
    for (int j = 0; j < 16; ++j) {
        float v = rs[j];
        v += __shfl_xor(v, 1); v += __shfl_xor(v, 2);
        v += __shfl_xor(v, 4); v += __shfl_xor(v, 8);
        rs[j] = v;
    }
    if (lane15 == 0) {
#pragma unroll
        for (int j = 0; j < 16; ++j)
            part[wave][(j >> 2) * 16 + quad * 4 + (j & 3)] = rs[j];
    }
    __syncthreads();
    if (tid < 64) {
        float ss = 0.f;
#pragma unroll
        for (int w = 0; w < 8; ++w) ss += part[w][tid];
        scf[tid] = 1.f / fmaxf(sqrtf(ss), 1e-12f);
    }
    __syncthreads();
#pragma unroll
    for (int mt = 0; mt < 4; ++mt)
#pragma unroll
        for (int r = 0; r < 4; ++r) {
            int row = mt * 16 + quad * 4 + r;
            float s = scf[row];
#pragma unroll
            for (int nt = 0; nt < 4; ++nt)
                T[row * 520 + wcol + nt * 16 + lane15] = f2fp8(acc[mt][nt][r] * s);
        }
    __syncthreads();
    // readback A-frag-major: wave = kh, lane's 16 B = frags kf=2kh (lo), 2kh+1 (hi)
#pragma unroll
    for (int gt = 0; gt < 4; ++gt) {
        int row = gt * 16 + lane15;
        i64 lo = *(const i64*)(T + row * 520 + (2 * wave) * 32 + quad * 8);
        i64 hi = *(const i64*)(T + row * 520 + (2 * wave + 1) * 32 + quad * 8);
        i64x2 st; st[0] = lo; st[1] = hi;
        int gtg = (m0 >> 4) + gt;
        *(i64x2*)(Az + ((size_t)(gtg * 8 + wave) * 64 + lane) * 16) = st;
    }
}

// ---------------- barrier-free fp8 Gram: 256x128 supertile, J>=2I masked ----------------
// R19: gt-major layout (R14), R15 micro-config: 4-wave blocks, single-buffered
// unroll-1 K-loop, launch_bounds(256,3) -> 72 VGPR, 3 blocks/CU. Grid 6336.
__global__ __launch_bounds__(256, 3) void gram_kernel(const unsigned char* __restrict__ Abase,
                                                      float* __restrict__ rowsum,
                                                      float* __restrict__ crossdot) {
    int px = blockIdx.x;
    int logical = (px & 7) * 792 + (px >> 3);     // 6336 = 8 * 792
    int tile = logical >> 1, sub = logical & 1;
    int p = tile / 1056;
    int t0 = tile - p * 1056;
    const unsigned char* Cm = Abase + (size_t)p * 2 * N_ROWS * OUT_DIM;

    int I = 0;
    while (t0 >= 64 - 2 * I) { t0 -= 64 - 2 * I; ++I; }
    int J = 2 * I + t0;
    int m0 = I * 256, n0 = J * 128;

    int tid = threadIdx.x;
    int wave = (tid >> 6) + sub * 4, lane = tid & 63;
    int lane15 = lane & 15, quad = lane >> 4;
    int wrow = (wave >> 1) * 64, wcol = (wave & 1) * 64;

    const unsigned char* Ca = Cm + (size_t)((m0 + wrow) >> 4) * 8192 + (size_t)lane * 16;
    const unsigned char* Cb = Cm + (size_t)((n0 + wcol) >> 4) * 8192 + (size_t)lane * 16;

    f32x4 acc[4][4];
#pragma unroll
    for (int mt = 0; mt < 4; ++mt)
#pragma unroll
        for (int nt = 0; nt < 4; ++nt)
            acc[mt][nt] = (f32x4){0.f, 0.f, 0.f, 0.f};

#pragma unroll 1
    for (int kh = 0; kh < 8; ++kh) {
        i64x2 a[4], b[4];
#pragma unroll
        for (int t = 0; t < 4; ++t) {
            a[t] = *(const i64x2*)(Ca + (size_t)t * 8192 + (size_t)kh * 1024);
            b[t] = *(const i64x2*)(Cb + (size_t)t * 8192 + (size_t)kh * 1024);
        }
#pragma unroll
        for (int half = 0; half < 2; ++half)
#pragma unroll
            for (int mt = 0; mt < 4; ++mt)
#pragma unroll
                for (int nt = 0; nt < 4; ++nt)
                    acc[mt][nt] = __builtin_amdgcn_mfma_f32_16x16x32_fp8_fp8(
                        a[mt][half], b[nt][half], acc[mt][nt], 0, 0, 0);
    }

    float* cdp = crossdot + (size_t)p * 2 * N_ROWS;
    float* rp  = rowsum  + (size_t)p * 2 * N_ROWS;

    float rs[16];
    float cs[4] = {0.f, 0.f, 0.f, 0.f};
#pragma unroll
    for (int j = 0; j < 16; ++j) rs[j] = 0.f;

    if (J >= 2 * I + 2) {
#pragma unroll
        for (int mt = 0; mt < 4; ++mt)
#pragma unroll
            for (int nt = 0; nt < 4; ++nt)
#pragma unroll
                for (int r = 0; r < 4; ++r) {
                    float e = __expf(2.f * acc[mt][nt][r]);
                    rs[mt * 4 + r] += e;
                    cs[nt] += e;
                }
        if (J >= 32 && ((J - 32) >> 1) == I) {
#pragma unroll
            for (int mt = 0; mt < 4; ++mt)
#pragma unroll
                for (int nt = 0; nt < 4; ++nt) {
                    int gcol = n0 + wcol + nt * 16 + lane15;
#pragma unroll
                    for (int r = 0; r < 4; ++r) {
                        int grow = m0 + wrow + mt * 16 + quad * 4 + r;
                        if (gcol == grow + N_ROWS) {
                            float s = acc[mt][nt][r];
                            cdp[grow] = s;
                            cdp[gcol] = s;
                        }
                    }
                }
        }
    } else {
#pragma unroll
        for (int mt = 0; mt < 4; ++mt)
#pragma unroll
            for (int nt = 0; nt < 4; ++nt) {
                int gcol = n0 + wcol + nt * 16 + lane15;
#pragma unroll
                for (int r = 0; r < 4; ++r) {
                    int grow = m0 + wrow + mt * 16 + quad * 4 + r;
                    if (grow < gcol) {
                        float e = __expf(2.f * acc[mt][nt][r]);
                        rs[mt * 4 + r] += e;
                        cs[nt] += e;
                    }
                }
            }
    }

#pragma unroll
    for (int j = 0; j < 16; ++j) {
        float v = rs[j];
        v += __shfl_xor(v, 1); v += __shfl_xor(v, 2);
        v += __shfl_xor(v, 4); v += __shfl_xor(v, 8);
        rs[j] = v;
    }
    if (lane15 == 0) {
#pragma unroll
        for (int j = 0; j < 16; ++j) {
            int grow = m0 + wrow + (j >> 2) * 16 + quad * 4 + (j & 3);
            atomicAdd(&rp[grow], rs[j]);
        }
    }
#pragma unroll
    for (int n = 0; n < 4; ++n) {
        float v = cs[n];
        v += __shfl_xor(v, 16); v += __shfl_xor(v, 32);
        cs[n] = v;
    }
    if (quad == 0) {
#pragma unroll
        for (int n = 0; n < 4; ++n) {
            int gcol = n0 + wcol + n * 16 + lane15;
            atomicAdd(&rp[gcol], cs[n]);
        }
    }
}

// ---------------- final loss reduction: 96 blocks + device atomic ----------------
__global__ void loss_kernel(const float* __restrict__ rowsum,
                            const float* __restrict__ crossdot, float* __restrict__ out) {
    int i = blockIdx.x * 256 + threadIdx.x;       // 96*256 = 24576 exactly
    float v = logf(rowsum[i]) - 2.f * crossdot[i];
#pragma unroll
    for (int m = 1; m < 64; m <<= 1) v += __shfl_xor(v, m);
    __shared__ float red[4];
    if ((threadIdx.x & 63) == 0) red[threadIdx.x >> 6] = v;
    __syncthreads();
    if (threadIdx.x == 0)
        atomicAdd(out, (red[0] + red[1] + red[2] + red[3]) * (1.f / 24576.f));
}

// ---------------- launch ----------------
extern "C" void kernel_launch(void* const* d_in, const int* in_sizes, int n_in,
                              void* d_out, int out_size, void* d_ws, size_t ws_size,
                              hipStream_t stream) {
    const float* doc0   = (const float*)d_in[0];
    const float* doc1   = (const float*)d_in[1];
    const float* doc2   = (const float*)d_in[2];
    const float* W1s    = (const float*)d_in[3];
    const float* b1s    = (const float*)d_in[4];
    const float* gammas = (const float*)d_in[5];
    const float* betas  = (const float*)d_in[6];
    const float* W2s    = (const float*)d_in[7];
    const float* b2s    = (const float*)d_in[8];
    float* out = (float*)d_out;

    char* base = (char*)d_ws;
    size_t off = 0;
    auto alloc = [&](size_t bytes) -> char* {
        char* r = base + off;
        off += (bytes + 255) & ~(size_t)255;
        return r;
    };

    unsigned short* Xb   = (unsigned short*)alloc((size_t)3 * N_ROWS * IN_DIM * 2);
    unsigned short* W1t  = (unsigned short*)alloc((size_t)6 * OUT_DIM * IN_DIM * 2);
    unsigned short* W2t  = (unsigned short*)alloc((size_t)6 * OUT_DIM * OUT_DIM * 2);
    unsigned short* H    = (unsigned short*)alloc((size_t)6 * N_ROWS * OUT_DIM * 2);
    unsigned short* Hb   = (unsigned short*)alloc((size_t)6 * N_ROWS * OUT_DIM * 2);
    unsigned char*  Abuf = (unsigned char*)Xb;    // Xb dead after gemm1
    char* zbase = alloc(24576 + 98304);
    float* stats  = (float*)zbase;
    float* rowsum = (float*)(zbase + 24576);
    float* cdot   = (float*)alloc((size_t)3 * 2 * N_ROWS * 4);

    if (ws_size < off) return;

    hipMemsetAsync(out, 0, sizeof(float), stream);   // loss accumulates atomically

    // 26112 conversion wave-units + 120 zero units = 26232 -> 6558 blocks
    prep<<<6558, 256, 0, stream>>>(doc0, doc1, doc2, W1s, W2s, Xb, W1t, W2t, zbase);

    gemm1_bn<<<768, 256, 0, stream>>>(Xb, W1t, b1s, H, stats);

    bn_apply<<<6144, 256, 0, stream>>>(H, Hb, stats, gammas, betas);

    gemm2_fused<<<384, 512, 0, stream>>>(Hb, W2t, b2s, Abuf);

    // supertile gram: 3 pairs x 1056 (J>=2I) tile-pairs, split into 4-wave blocks
    gram_kernel<<<6336, 256, 0, stream>>>(Abuf, rowsum, cdot);

    loss_kernel<<<96, 256, 0, stream>>>(rowsum, cdot, out);
}

// Round 7
// 276.760 us; speedup vs baseline: 1.2478x; 1.0255x over previous
//
#include <hip/hip_runtime.h>
#include <hip/hip_bf16.h>
#include <hip/hip_fp8.h>

#define N_ROWS 4096
#define IN_DIM 768
#define OUT_DIM 512

// All GEMM operands fragment-major. bf16 (16x16 MFMA): unit = gt*(K/32)+kf,
// byte = (unit*64+lane)*16; lane: row = gt*16+(lane&15), k = kf*32+(lane>>4)*8+j.
// Abuf (fp8) gt-major: gt-chunk = 8192 B, within: kh*1024 + lane*16 (16 B/lane
// = fp8 frag pair kf=2kh lo / 2kh+1 hi).
// R20: LDS-pipelined gram. R13-R19 established the barrier-free direct-load
//   structure is pinned at ~37% MfmaUtil (= the documented m97 2-phase
//   ceiling) across 6 schedule variants. Fix per T3/T14: stage kh-chunks into
//   LDS via global_load_lds issued EARLY (before ds_read+MFMA of current
//   chunk), drained by __syncthreads' automatic vmcnt(0) ~700 cyc later.
//   8-wave blocks, 256x128 supertile, 24 KB/chunk dbuf (48 KB LDS),
//   launch_bounds(512,4) -> 2 blocks/CU, 4 waves/SIMD. Fragment layout is
//   global_load_lds-native (wave-uniform dest + lane*16) and conflict-free on
//   readback. gemm1/gemm2/prep/bn/loss = R19 (best known).

using bf16x8 = __attribute__((ext_vector_type(8))) short;
using f32x4  = __attribute__((ext_vector_type(4))) float;
using i64    = long;
using i64x2  = __attribute__((ext_vector_type(2))) long;

__device__ __constant__ int c_docmap[6] = {0, 1, 0, 2, 1, 2};

__device__ inline unsigned short f2bf(float f) {
    __hip_bfloat16 h = __float2bfloat16(f);
    return reinterpret_cast<unsigned short&>(h);
}
__device__ inline float bf2f(unsigned short u) {
    return __uint_as_float((unsigned int)u << 16);
}
__device__ inline unsigned char f2fp8(float f) {
    __hip_fp8_e4m3 t(f);           // OCP e4m3fn, RNE+sat
    return t.__x;
}
__device__ inline uint4 pack8bf(const float* v) {
    uint4 o;
    unsigned short* p = (unsigned short*)&o;
#pragma unroll
    for (int j = 0; j < 8; ++j) p[j] = f2bf(v[j]);
    return o;
}

// ---------------- prep: conversions to fragment-major + zero-init ----------------
__global__ __launch_bounds__(256) void prep(
    const float* __restrict__ d0, const float* __restrict__ d1,
    const float* __restrict__ d2, const float* __restrict__ W1s,
    const float* __restrict__ W2s, unsigned short* __restrict__ Xb,
    unsigned short* __restrict__ W1t, unsigned short* __restrict__ W2t,
    char* __restrict__ zbase) {
    int wunit = blockIdx.x * 4 + (threadIdx.x >> 6);
    int lane = threadIdx.x & 63;
    int lane15 = lane & 15, quad = lane >> 4;
    if (wunit < 18432) {
        int d = wunit / 6144, u = wunit % 6144;       // 256 gt x 24 kf
        int gt = u / 24, kf = u % 24;
        const float* src = (d == 0) ? d0 : ((d == 1) ? d1 : d2);
        const float* s = src + (size_t)(gt * 16 + lane15) * IN_DIM + kf * 32 + quad * 8;
        float4 a = *(const float4*)s, b = *(const float4*)(s + 4);
        float v[8] = {a.x, a.y, a.z, a.w, b.x, b.y, b.z, b.w};
        *(uint4*)(Xb + (size_t)d * N_ROWS * IN_DIM + (size_t)u * 512 + lane * 8) = pack8bf(v);
    } else if (wunit < 23040) {
        int v0 = wunit - 18432;
        int z = v0 / 768, u = v0 % 768;               // 32 gt x 24 kf
        int gt = u / 24, kf = u % 24;
        int n = gt * 16 + lane15;
        int k0 = kf * 32 + quad * 8;
        const float* W = W1s + (size_t)z * IN_DIM * OUT_DIM;
        float v[8];
#pragma unroll
        for (int j = 0; j < 8; ++j) v[j] = W[(size_t)(k0 + j) * OUT_DIM + n];
        *(uint4*)(W1t + (size_t)z * OUT_DIM * IN_DIM + (size_t)u * 512 + lane * 8) = pack8bf(v);
    } else if (wunit < 26112) {
        int v0 = wunit - 23040;
        int z = v0 / 512, u = v0 % 512;               // 32 gt x 16 kf
        int gt = u / 16, kf = u % 16;
        int n = gt * 16 + lane15;
        int k0 = kf * 32 + quad * 8;
        const float* W = W2s + (size_t)z * OUT_DIM * OUT_DIM;
        float v[8];
#pragma unroll
        for (int j = 0; j < 8; ++j) v[j] = W[(size_t)(k0 + j) * OUT_DIM + n];
        *(uint4*)(W2t + (size_t)z * OUT_DIM * OUT_DIM + (size_t)u * 512 + lane * 8) = pack8bf(v);
    } else {
        size_t b = (size_t)(wunit - 26112) * 1024 + (size_t)lane * 16;
        if (b < (size_t)(24576 + 98304))
            *(float4*)(zbase + b) = (float4){0.f, 0.f, 0.f, 0.f};
    }
}

// ---------------- GEMM1: 256x128 supertile, barrier-free, BF16 out + BN-stats ----------------
// 4-wave blocks, grid 768 (= 8 * 96), XCD-contiguous, double-buffered (R14).
__global__ __launch_bounds__(256) void gemm1_bn(
    const unsigned short* __restrict__ Xb, const unsigned short* __restrict__ W1t,
    const float* __restrict__ biasAll, unsigned short* __restrict__ H,
    float* __restrict__ stats) {
    const int NKF = IN_DIM / 32;   // 24
    int px = blockIdx.x;
    int logical = (px & 7) * 96 + (px >> 3);      // 768 = 8 * 96
    int T = logical >> 1, sub = logical & 1;
    int z = T >> 6, rem = T & 63;
    int m0 = (rem >> 2) * 256, n0 = (rem & 3) * 128;
    const unsigned short* A = Xb + (size_t)c_docmap[z] * N_ROWS * IN_DIM;
    const unsigned short* B = W1t + (size_t)z * OUT_DIM * IN_DIM;
    const float* bz = biasAll + (size_t)z * OUT_DIM;
    unsigned short* C = H + (size_t)z * N_ROWS * OUT_DIM;

    int tid = threadIdx.x;
    int wave = (tid >> 6) + sub * 4, lane = tid & 63;
    int lane15 = lane & 15, quad = lane >> 4;
    int wrow = (wave >> 1) * 64, wcol = (wave & 1) * 64;

    const unsigned short* Ca = A + (size_t)((m0 + wrow) >> 4) * NKF * 512 + (size_t)lane * 8;
    const unsigned short* Cb = B + (size_t)((n0 + wcol) >> 4) * NKF * 512 + (size_t)lane * 8;

    f32x4 acc[4][4];
#pragma unroll
    for (int mt = 0; mt < 4; ++mt)
#pragma unroll
        for (int nt = 0; nt < 4; ++nt)
            acc[mt][nt] = (f32x4){0.f, 0.f, 0.f, 0.f};

    bf16x8 aC[4], bC[4], aN[4], bN[4];
#pragma unroll
    for (int t = 0; t < 4; ++t) {
        aC[t] = *(const bf16x8*)(Ca + (size_t)t * NKF * 512);
        bC[t] = *(const bf16x8*)(Cb + (size_t)t * NKF * 512);
    }
#pragma unroll
    for (int kf = 0; kf < NKF; ++kf) {
        if (kf < NKF - 1) {
#pragma unroll
            for (int t = 0; t < 4; ++t) {
                aN[t] = *(const bf16x8*)(Ca + (size_t)t * NKF * 512 + (kf + 1) * 512);
                bN[t] = *(const bf16x8*)(Cb + (size_t)t * NKF * 512 + (kf + 1) * 512);
            }
        }
        __builtin_amdgcn_s_setprio(1);
#pragma unroll
        for (int mt = 0; mt < 4; ++mt)
#pragma unroll
            for (int nt = 0; nt < 4; ++nt)
                acc[mt][nt] = __builtin_amdgcn_mfma_f32_16x16x32_bf16(aC[mt], bC[nt], acc[mt][nt], 0, 0, 0);
        __builtin_amdgcn_s_setprio(0);
#pragma unroll
        for (int t = 0; t < 4; ++t) { aC[t] = aN[t]; bC[t] = bN[t]; }
    }

    float s1[4] = {0.f, 0.f, 0.f, 0.f}, s2[4] = {0.f, 0.f, 0.f, 0.f};
#pragma unroll
    for (int nt = 0; nt < 4; ++nt) {
        int col = n0 + wcol + nt * 16 + lane15;
        float bv = bz[col];
#pragma unroll
        for (int mt = 0; mt < 4; ++mt)
#pragma unroll
            for (int r = 0; r < 4; ++r) {
                int row = m0 + wrow + mt * 16 + quad * 4 + r;
                float v = acc[mt][nt][r] + bv;
                C[(size_t)row * OUT_DIM + col] = f2bf(v);
                s1[nt] += v; s2[nt] += v * v;       // stats from fp32 (exact)
            }
    }
#pragma unroll
    for (int nt = 0; nt < 4; ++nt) {
        float a = s1[nt], b = s2[nt];
        a += __shfl_xor(a, 16); a += __shfl_xor(a, 32);
        b += __shfl_xor(b, 16); b += __shfl_xor(b, 32);
        if (quad == 0) {
            int col = n0 + wcol + nt * 16 + lane15;
            atomicAdd(&stats[((size_t)z * OUT_DIM + col) * 2 + 0], a);
            atomicAdd(&stats[((size_t)z * OUT_DIM + col) * 2 + 1], b);
        }
    }
}

// ---------------- BN apply + ReLU: bf16 H row-major -> bf16 Hb FRAG-MAJOR ----------------
__global__ __launch_bounds__(256) void bn_apply(
    const unsigned short* __restrict__ H, unsigned short* __restrict__ Hb,
    const float* __restrict__ stats, const float* __restrict__ gammas,
    const float* __restrict__ betas) {
    int wunit = blockIdx.x * 4 + (threadIdx.x >> 6);
    if (wunit >= 24576) return;
    int lane = threadIdx.x & 63;
    int lane15 = lane & 15, quad = lane >> 4;
    int z = wunit / 4096, u = wunit % 4096;       // 256 gt x 16 kf
    int gt = u / 16, kf = u % 16;
    int row = gt * 16 + lane15;
    int k = kf * 32 + quad * 8;
    uint4 hu = *(const uint4*)(H + ((size_t)z * N_ROWS + row) * OUT_DIM + k);
    unsigned int w[4] = {hu.x, hu.y, hu.z, hu.w};
    float v[8];
#pragma unroll
    for (int j = 0; j < 8; ++j) {
        unsigned short us = (j & 1) ? (unsigned short)(w[j >> 1] >> 16)
                                    : (unsigned short)(w[j >> 1] & 0xffff);
        size_t sc = (size_t)z * OUT_DIM + k + j;
        float mu = stats[sc * 2 + 0] * (1.f / N_ROWS);
        float var = stats[sc * 2 + 1] * (1.f / N_ROWS) - mu * mu;
        float s = gammas[sc] * rsqrtf(var + 1e-5f);
        v[j] = fmaxf(fmaf(bf2f(us), s, betas[sc] - mu * s), 0.f);
    }
    *(uint4*)(Hb + (size_t)z * N_ROWS * OUT_DIM + (size_t)u * 512 + lane * 8) = pack8bf(v);
}

// ---------------- GEMM2 fused: barrier-free K-loop + l2norm/fp8/transpose epilogue ----------------
// 64 rows x 512 cols per block. 1D grid 384, XCD-contiguous (z-major).
// Double-buffered (R14); 512 thr (cross-wave LDS epilogue). gt-major Az write.
__global__ __launch_bounds__(512) void gemm2_fused(
    const unsigned short* __restrict__ Hb, const unsigned short* __restrict__ W2t,
    const float* __restrict__ biasAll, unsigned char* __restrict__ Abuf) {
    const int NKF = OUT_DIM / 32;  // 16
    int px = blockIdx.x;
    int L = (px & 7) * 48 + (px >> 3);            // 384 = 8 * 48
    int z = L >> 6;
    int m0 = (L & 63) * 64;
    const unsigned short* A = Hb + (size_t)z * N_ROWS * OUT_DIM;
    const unsigned short* B = W2t + (size_t)z * OUT_DIM * OUT_DIM;
    const float* bz = biasAll + (size_t)z * OUT_DIM;
    unsigned char* Az = Abuf + (size_t)z * N_ROWS * OUT_DIM;

    int tid = threadIdx.x;
    int wave = tid >> 6, lane = tid & 63;
    int lane15 = lane & 15, quad = lane >> 4;
    int wcol = wave * 64;

    const unsigned short* Ca = A + (size_t)(m0 >> 4) * NKF * 512 + (size_t)lane * 8;
    const unsigned short* Cb = B + (size_t)(wave * 4) * NKF * 512 + (size_t)lane * 8;

    f32x4 acc[4][4];
#pragma unroll
    for (int mt = 0; mt < 4; ++mt)
#pragma unroll
        for (int nt = 0; nt < 4; ++nt)
            acc[mt][nt] = (f32x4){0.f, 0.f, 0.f, 0.f};

    bf16x8 aC[4], bC[4], aN[4], bN[4];
#pragma unroll
    for (int t = 0; t < 4; ++t) {
        aC[t] = *(const bf16x8*)(Ca + (size_t)t * NKF * 512);
        bC[t] = *(const bf16x8*)(Cb + (size_t)t * NKF * 512);
    }
#pragma unroll
    for (int kf = 0; kf < NKF; ++kf) {
        if (kf < NKF - 1) {
#pragma unroll
            for (int t = 0; t < 4; ++t) {
                aN[t] = *(const bf16x8*)(Ca + (size_t)t * NKF * 512 + (kf + 1) * 512);
                bN[t] = *(const bf16x8*)(Cb + (size_t)t * NKF * 512 + (kf + 1) * 512);
            }
        }
#pragma unroll
        for (int mt = 0; mt < 4; ++mt)
#pragma unroll
            for (int nt = 0; nt < 4; ++nt)
                acc[mt][nt] = __builtin_amdgcn_mfma_f32_16x16x32_bf16(aC[mt], bC[nt], acc[mt][nt], 0, 0, 0);
#pragma unroll
        for (int t = 0; t < 4; ++t) { aC[t] = aN[t]; bC[t] = bN[t]; }
    }

    // ---- epilogue (validated R11/R12): bias, row sumsq, normalize, fp8, transpose ----
    __shared__ float part[8][64];
    __shared__ float scf[64];
    __shared__ __attribute__((aligned(16))) unsigned char T[64 * 520];

    float rs[16];
#pragma unroll
    for (int j = 0; j < 16; ++j) rs[j] = 0.f;
#pragma unroll
    for (int nt = 0; nt < 4; ++nt) {
        float bv = bz[wcol + nt * 16 + lane15];
#pragma unroll
        for (int mt = 0; mt < 4; ++mt)
#pragma unroll
            for (int r = 0; r < 4; ++r) {
                float v = acc[mt][nt][r] + bv;
                acc[mt][nt][r] = v;
                rs[mt * 4 + r] += v * v;
            }
    }
#pragma unroll
    for (int j = 0; j < 16; ++j) {
        float v = rs[j];
        v += __shfl_xor(v, 1); v += __shfl_xor(v, 2);
        v += __shfl_xor(v, 4); v += __shfl_xor(v, 8);
        rs[j] = v;
    }
    if (lane15 == 0) {
#pragma unroll
        for (int j = 0; j < 16; ++j)
            part[wave][(j >> 2) * 16 + quad * 4 + (j & 3)] = rs[j];
    }
    __syncthreads();
    if (tid < 64) {
        float ss = 0.f;
#pragma unroll
        for (int w = 0; w < 8; ++w) ss += part[w][tid];
        scf[tid] = 1.f / fmaxf(sqrtf(ss), 1e-12f);
    }
    __syncthreads();
#pragma unroll
    for (int mt = 0; mt < 4; ++mt)
#pragma unroll
        for (int r = 0; r < 4; ++r) {
            int row = mt * 16 + quad * 4 + r;
            float s = scf[row];
#pragma unroll
            for (int nt = 0; nt < 4; ++nt)
                T[row * 520 + wcol + nt * 16 + lane15] = f2fp8(acc[mt][nt][r] * s);
        }
    __syncthreads();
    // readback A-frag-major: wave = kh, lane's 16 B = frags kf=2kh (lo), 2kh+1 (hi)
#pragma unroll
    for (int gt = 0; gt < 4; ++gt) {
        int row = gt * 16 + lane15;
        i64 lo = *(const i64*)(T + row * 520 + (2 * wave) * 32 + quad * 8);
        i64 hi = *(const i64*)(T + row * 520 + (2 * wave + 1) * 32 + quad * 8);
        i64x2 st; st[0] = lo; st[1] = hi;
        int gtg = (m0 >> 4) + gt;
        *(i64x2*)(Az + ((size_t)(gtg * 8 + wave) * 64 + lane) * 16) = st;
    }
}

// ---------------- LDS-pipelined fp8 Gram: 256x128 supertile, J>=2I masked ----------------
// R20: 8-wave blocks, grid 3168 XCD-contiguous. Per kh (K=64): 24 chunks of
// 1024 B (16 A-gt + 8 B-gt) staged via global_load_lds (3 per wave), double-
// buffered in 48 KB LDS. Early-issue: stage(kh+1) issued BEFORE ds_read+MFMA
// of kh; __syncthreads' automatic vmcnt(0) drains ~700 cyc later (T3/T14).
// launch_bounds(512,4): 2 blocks/CU, 4 waves/SIMD.
__global__ __launch_bounds__(512, 4) void gram_kernel(const unsigned char* __restrict__ Abase,
                                                      float* __restrict__ rowsum,
                                                      float* __restrict__ crossdot) {
    int px = blockIdx.x;
    int logical = (px & 7) * 396 + (px >> 3);     // 3168 = 8 * 396
    int p = logical / 1056;
    int t0 = logical - p * 1056;
    const unsigned char* Cm = Abase + (size_t)p * 2 * N_ROWS * OUT_DIM;

    int I = 0;
    while (t0 >= 64 - 2 * I) { t0 -= 64 - 2 * I; ++I; }
    int J = 2 * I + t0;
    int m0 = I * 256, n0 = J * 128;

    int tid = threadIdx.x;
    int wave = tid >> 6, lane = tid & 63;
    int lane15 = lane & 15, quad = lane >> 4;
    int wrow = (wave >> 1) * 64, wcol = (wave & 1) * 64;

    __shared__ __attribute__((aligned(16))) unsigned char lds[2][24 * 1024];

    // staging: chunks 0-15 = A gt tiles (rows m0..m0+255), 16-23 = B gt tiles
    const unsigned char* gA = Cm + (size_t)(m0 >> 4) * 8192;
    const unsigned char* gB = Cm + (size_t)(n0 >> 4) * 8192;
    const unsigned char* gsrc[3];
    int cdst[3];
#pragma unroll
    for (int j = 0; j < 3; ++j) {
        int c = wave * 3 + j;
        gsrc[j] = ((c < 16) ? (gA + (size_t)c * 8192) : (gB + (size_t)(c - 16) * 8192))
                  + (size_t)lane * 16;
        cdst[j] = c * 1024;
    }

    typedef __attribute__((address_space(1))) const unsigned int gu32;
    typedef __attribute__((address_space(3))) unsigned int su32;

    // prologue: stage kh=0 into buf 0
#pragma unroll
    for (int j = 0; j < 3; ++j)
        __builtin_amdgcn_global_load_lds((gu32*)(const void*)gsrc[j],
                                         (su32*)(void*)(&lds[0][cdst[j]]), 16, 0, 0);
    __syncthreads();

    f32x4 acc[4][4];
#pragma unroll
    for (int mt = 0; mt < 4; ++mt)
#pragma unroll
        for (int nt = 0; nt < 4; ++nt)
            acc[mt][nt] = (f32x4){0.f, 0.f, 0.f, 0.f};

    int aoff = (wrow >> 4) * 1024 + lane * 16;          // A frag base in LDS
    int boff = (16 + (wcol >> 4)) * 1024 + lane * 16;   // B frag base in LDS

#pragma unroll 1
    for (int kh = 0; kh < 8; ++kh) {
        int cur = kh & 1;
        if (kh < 7) {
            // early-issue next chunk's staging into the other buffer
#pragma unroll
            for (int j = 0; j < 3; ++j)
                __builtin_amdgcn_global_load_lds(
                    (gu32*)(const void*)(gsrc[j] + (size_t)(kh + 1) * 1024),
                    (su32*)(void*)(&lds[cur ^ 1][cdst[j]]), 16, 0, 0);
        }
        i64x2 a[4], b[4];
#pragma unroll
        for (int t = 0; t < 4; ++t) {
            a[t] = *(const i64x2*)(&lds[cur][aoff + t * 1024]);
            b[t] = *(const i64x2*)(&lds[cur][boff + t * 1024]);
        }
        __builtin_amdgcn_s_setprio(1);
#pragma unroll
        for (int half = 0; half < 2; ++half)
#pragma unroll
            for (int mt = 0; mt < 4; ++mt)
#pragma unroll
                for (int nt = 0; nt < 4; ++nt)
                    acc[mt][nt] = __builtin_amdgcn_mfma_f32_16x16x32_fp8_fp8(
                        a[mt][half], b[nt][half], acc[mt][nt], 0, 0, 0);
        __builtin_amdgcn_s_setprio(0);
        __syncthreads();   // drains this thread's stage loads (vmcnt 0) + syncs
    }

    float* cdp = crossdot + (size_t)p * 2 * N_ROWS;
    float* rp  = rowsum  + (size_t)p * 2 * N_ROWS;

    float rs[16];
    float cs[4] = {0.f, 0.f, 0.f, 0.f};
#pragma unroll
    for (int j = 0; j < 16; ++j) rs[j] = 0.f;

    if (J >= 2 * I + 2) {
#pragma unroll
        for (int mt = 0; mt < 4; ++mt)
#pragma unroll
            for (int nt = 0; nt < 4; ++nt)
#pragma unroll
                for (int r = 0; r < 4; ++r) {
                    float e = __expf(2.f * acc[mt][nt][r]);
                    rs[mt * 4 + r] += e;
                    cs[nt] += e;
                }
        if (J >= 32 && ((J - 32) >> 1) == I) {
#pragma unroll
            for (int mt = 0; mt < 4; ++mt)
#pragma unroll
                for (int nt = 0; nt < 4; ++nt) {
                    int gcol = n0 + wcol + nt * 16 + lane15;
#pragma unroll
                    for (int r = 0; r < 4; ++r) {
                        int grow = m0 + wrow + mt * 16 + quad * 4 + r;
                        if (gcol == grow + N_ROWS) {
                            float s = acc[mt][nt][r];
                            cdp[grow] = s;
                            cdp[gcol] = s;
                        }
                    }
                }
        }
    } else {
#pragma unroll
        for (int mt = 0; mt < 4; ++mt)
#pragma unroll
            for (int nt = 0; nt < 4; ++nt) {
                int gcol = n0 + wcol + nt * 16 + lane15;
#pragma unroll
                for (int r = 0; r < 4; ++r) {
                    int grow = m0 + wrow + mt * 16 + quad * 4 + r;
                    if (grow < gcol) {
                        float e = __expf(2.f * acc[mt][nt][r]);
                        rs[mt * 4 + r] += e;
                        cs[nt] += e;
                    }
                }
            }
    }

#pragma unroll
    for (int j = 0; j < 16; ++j) {
        float v = rs[j];
        v += __shfl_xor(v, 1); v += __shfl_xor(v, 2);
        v += __shfl_xor(v, 4); v += __shfl_xor(v, 8);
        rs[j] = v;
    }
    if (lane15 == 0) {
#pragma unroll
        for (int j = 0; j < 16; ++j) {
            int grow = m0 + wrow + (j >> 2) * 16 + quad * 4 + (j & 3);
            atomicAdd(&rp[grow], rs[j]);
        }
    }
#pragma unroll
    for (int n = 0; n < 4; ++n) {
        float v = cs[n];
        v += __shfl_xor(v, 16); v += __shfl_xor(v, 32);
        cs[n] = v;
    }
    if (quad == 0) {
#pragma unroll
        for (int n = 0; n < 4; ++n) {
            int gcol = n0 + wcol + n * 16 + lane15;
            atomicAdd(&rp[gcol], cs[n]);
        }
    }
}

// ---------------- final loss reduction: 96 blocks + device atomic ----------------
__global__ void loss_kernel(const float* __restrict__ rowsum,
                            const float* __restrict__ crossdot, float* __restrict__ out) {
    int i = blockIdx.x * 256 + threadIdx.x;       // 96*256 = 24576 exactly
    float v = logf(rowsum[i]) - 2.f * crossdot[i];
#pragma unroll
    for (int m = 1; m < 64; m <<= 1) v += __shfl_xor(v, m);
    __shared__ float red[4];
    if ((threadIdx.x & 63) == 0) red[threadIdx.x >> 6] = v;
    __syncthreads();
    if (threadIdx.x == 0)
        atomicAdd(out, (red[0] + red[1] + red[2] + red[3]) * (1.f / 24576.f));
}

// ---------------- launch ----------------
extern "C" void kernel_launch(void* const* d_in, const int* in_sizes, int n_in,
                              void* d_out, int out_size, void* d_ws, size_t ws_size,
                              hipStream_t stream) {
    const float* doc0   = (const float*)d_in[0];
    const float* doc1   = (const float*)d_in[1];
    const float* doc2   = (const float*)d_in[2];
    const float* W1s    = (const float*)d_in[3];
    const float* b1s    = (const float*)d_in[4];
    const float* gammas = (const float*)d_in[5];
    const float* betas  = (const float*)d_in[6];
    const float* W2s    = (const float*)d_in[7];
    const float* b2s    = (const float*)d_in[8];
    float* out = (float*)d_out;

    char* base = (char*)d_ws;
    size_t off = 0;
    auto alloc = [&](size_t bytes) -> char* {
        char* r = base + off;
        off += (bytes + 255) & ~(size_t)255;
        return r;
    };

    unsigned short* Xb   = (unsigned short*)alloc((size_t)3 * N_ROWS * IN_DIM * 2);
    unsigned short* W1t  = (unsigned short*)alloc((size_t)6 * OUT_DIM * IN_DIM * 2);
    unsigned short* W2t  = (unsigned short*)alloc((size_t)6 * OUT_DIM * OUT_DIM * 2);
    unsigned short* H    = (unsigned short*)alloc((size_t)6 * N_ROWS * OUT_DIM * 2);
    unsigned short* Hb   = (unsigned short*)alloc((size_t)6 * N_ROWS * OUT_DIM * 2);
    unsigned char*  Abuf = (unsigned char*)Xb;    // Xb dead after gemm1
    char* zbase = alloc(24576 + 98304);
    float* stats  = (float*)zbase;
    float* rowsum = (float*)(zbase + 24576);
    float* cdot   = (float*)alloc((size_t)3 * 2 * N_ROWS * 4);

    if (ws_size < off) return;

    hipMemsetAsync(out, 0, sizeof(float), stream);   // loss accumulates atomically

    // 26112 conversion wave-units + 120 zero units = 26232 -> 6558 blocks
    prep<<<6558, 256, 0, stream>>>(doc0, doc1, doc2, W1s, W2s, Xb, W1t, W2t, zbase);

    gemm1_bn<<<768, 256, 0, stream>>>(Xb, W1t, b1s, H, stats);

    bn_apply<<<6144, 256, 0, stream>>>(H, Hb, stats, gammas, betas);

    gemm2_fused<<<384, 512, 0, stream>>>(Hb, W2t, b2s, Abuf);

    // supertile gram: 3 pairs x 1056 (J>=2I) tile-pairs, 8-wave LDS-pipelined
    gram_kernel<<<3168, 512, 0, stream>>>(Abuf, rowsum, cdot);

    loss_kernel<<<96, 256, 0, stream>>>(rowsum, cdot, out);
}